// Round 4
// baseline (2881.971 us; speedup 1.0000x reference)
//
#include <hip/hip_runtime.h>

// Problem: B=128, T=512, I=512, H=2048, O=512, steps = T-2 = 510.
// Persistent-RNN, R4: per-producer flags + per-wave pipelined h exchange.
//   - hbuf re-laid out as 2KB chunk-tiles [parity][cg][rg][16 rows x 64 cols],
//     XOR-swizzled (16B unit ^= row&7) by the producer so the LDS-DMA's rigid
//     base+lane*16 dest yields conflict-acceptable MFMA A-frag reads.
//   - Each consumer WAVE owns its k-quarter = 8 chunks = 8 producers; polls
//     each producer's private flag (single writer, plain coherent store, no
//     atomic RMW) and issues that chunk's DMA immediately -> DMA pipelines
//     behind the remaining polls. One explicit s_waitcnt vmcnt(0) before the
//     h-MFMAs.
//   - x loads direct global->VGPR (no LDS staging); their latency hides
//     under the first poll's implicit vmcnt drain.
//   - 2 barriers/step instead of 3; no block-wide pre-DMA barrier at all.
#define Bsz 128
#define Tsz 512
#define Isz 512
#define Hsz 2048
#define Osz 512
#define STEPS 510

typedef short short8 __attribute__((ext_vector_type(8)));
typedef float floatx4 __attribute__((ext_vector_type(4)));

// fp32 -> bf16 round-to-nearest-even (finite inputs only)
__device__ __forceinline__ unsigned short f2bf(float f) {
  unsigned int u = __builtin_bit_cast(unsigned int, f);
  u += 0x7FFFu + ((u >> 16) & 1u);
  return (unsigned short)(u >> 16);
}

// async global->LDS, 16B/lane; global src is per-lane (pass ptr + lane*16B),
// LDS dest is wave-uniform base (HW adds lane*16). AUX=0x11 (SC0|SC1):
// device-coherent read from L3, bypassing stale L1/L2.
template <int AUX>
__device__ __forceinline__ void gload_lds16(const void* g, void* l) {
  __builtin_amdgcn_global_load_lds(
      (const __attribute__((address_space(1))) void*)g,
      (__attribute__((address_space(3))) void*)l, 16, 0, AUX);
}

__global__ __launch_bounds__(256, 1)
void rnn_kernel(const float* __restrict__ x, const float* __restrict__ h0v,
                const float* __restrict__ W_ih, const float* __restrict__ b_ih,
                const float* __restrict__ W_hh, const float* __restrict__ b_hh,
                unsigned short* __restrict__ hbuf,  // [2][32 cg][8 rg][1024] swizzled bf16 tiles
                float* __restrict__ hfinal,         // [128][2048] f32
                unsigned int* __restrict__ flags)   // [32 cg][8 rg] step counters
{
  __shared__ short h_lds[4 * 8192];   // 64 KB: per-wave 8 chunk-tiles [16][64], swizzled
  __shared__ float red_lds[4 * 1024]; // 16 KB: k-split partials
  __shared__ int pad_lds[16];

  const int tid = threadIdx.x;
  const int lane = tid & 63;
  const int wv = tid >> 6;    // wave 0..3 -> k-quarter
  const int m16 = lane & 15;  // MFMA: A row / B col / C col
  const int quad = lane >> 4;
  const int m7 = m16 & 7;
  const int rg = blockIdx.x & 7;   // row group
  const int cg = blockIdx.x >> 3;  // col group 0..31
  const int b0 = rg * 16;
  const int c0 = cg * 64;
  const int kq = wv * 512;   // W_hh k-range for this wave
  const int kqx = wv * 128;  // W_ih k-range
  const int wvoff = wv * 8192;  // this wave's h_lds region (shorts)

  // ---- one-time: weight slices -> bf16 B-fragments in registers ----
  // B-frag: lane holds B[k = quad*8 + j][n = lane&15]
  short8 wf[16][4];  // [kchunk within quarter][ntile]
  short8 wih[4][4];
#pragma unroll
  for (int nt = 0; nt < 4; ++nt) {
    const int wrow = c0 + nt * 16 + m16;  // W row = output col j
    const float* base = W_hh + (size_t)wrow * Hsz + kq + quad * 8;
#pragma unroll
    for (int kc = 0; kc < 16; ++kc) {
      short8 v;
#pragma unroll
      for (int j = 0; j < 8; ++j) v[j] = (short)f2bf(base[kc * 32 + j]);
      wf[kc][nt] = v;
    }
    const float* basex = W_ih + (size_t)wrow * Isz + kqx + quad * 8;
#pragma unroll
    for (int kc = 0; kc < 4; ++kc) {
      short8 v;
#pragma unroll
      for (int j = 0; j < 8; ++j) v[j] = (short)f2bf(basex[kc * 32 + j]);
      wih[kc][nt] = v;
    }
  }

  // reduce-phase assignment: thread handles (row=tid>>4, 4 cols at 4*(tid&15))
  const int rrow = tid >> 4;
  const int rcb = (tid & 15) * 4;
  float bias[4];
#pragma unroll
  for (int i = 0; i < 4; ++i) bias[i] = b_ih[c0 + rcb + i] + b_hh[c0 + rcb + i];

  if (tid < 16)
    pad_lds[tid] = (int)x[(size_t)(b0 + tid) * (Tsz * Isz) + (size_t)(Tsz - 1) * Isz];

  // h_0 = h0 broadcast into this wave's 8 tiles (swizzled layout)
  for (int i = lane; i < 1024; i += 64) {  // i = 16B-unit index in wave region
    const int c = i >> 7;          // tile 0..7
    const int r = (i >> 3) & 15;   // row 0..15
    const int u = i & 7;           // unit 0..7
    const int k = kq + c * 64 + u * 8;
    short8 v;
#pragma unroll
    for (int j = 0; j < 8; ++j) v[j] = (short)f2bf(h0v[k + j]);
    *reinterpret_cast<short8*>(&h_lds[wvoff + c * 1024 + r * 64 + (u ^ (r & 7)) * 8]) = v;
  }

  for (int t = 0; t < STEPS; ++t) {
    const bool have_next = (t + 1) < STEPS;

    // x for this step: direct global->VGPR (latency hides under first poll)
    const float* xp = x + (size_t)(b0 + m16) * (Tsz * Isz) + (size_t)t * Isz + kqx + quad * 8;
    float4 xv[8];
#pragma unroll
    for (int kcc = 0; kcc < 4; ++kcc) {
      xv[2 * kcc] = *reinterpret_cast<const float4*>(xp + kcc * 32);
      xv[2 * kcc + 1] = *reinterpret_cast<const float4*>(xp + kcc * 32 + 4);
    }

    if (t > 0) {
      // per-wave: poll my 8 producers, DMA each 2KB chunk as it becomes ready
      const unsigned short* hsrcp = hbuf + (size_t)(t & 1) * (Bsz * Hsz);
#pragma unroll
      for (int c = 0; c < 8; ++c) {
        const int cgp = wv * 8 + c;
        const unsigned int* fp = flags + cgp * 8 + rg;
        while (__hip_atomic_load(fp, __ATOMIC_RELAXED, __HIP_MEMORY_SCOPE_AGENT) < (unsigned)t)
          __builtin_amdgcn_s_sleep(1);
        const unsigned short* src = hsrcp + (size_t)(cgp * 8 + rg) * 1024;
        gload_lds16<0x11>(src + lane * 8, &h_lds[wvoff + c * 1024]);
        gload_lds16<0x11>(src + 512 + lane * 8, &h_lds[wvoff + c * 1024 + 512]);
      }
    }

    // convert x to A-frags (xv already drained by poll-loop waits)
    short8 xa[4];
#pragma unroll
    for (int kcc = 0; kcc < 4; ++kcc) {
      short8 a;
      a[0] = (short)f2bf(xv[2 * kcc].x);
      a[1] = (short)f2bf(xv[2 * kcc].y);
      a[2] = (short)f2bf(xv[2 * kcc].z);
      a[3] = (short)f2bf(xv[2 * kcc].w);
      a[4] = (short)f2bf(xv[2 * kcc + 1].x);
      a[5] = (short)f2bf(xv[2 * kcc + 1].y);
      a[6] = (short)f2bf(xv[2 * kcc + 1].z);
      a[7] = (short)f2bf(xv[2 * kcc + 1].w);
      xa[kcc] = a;
    }

    floatx4 acc[4];
#pragma unroll
    for (int nt = 0; nt < 4; ++nt) {
      floatx4 zero = {0.f, 0.f, 0.f, 0.f};
      acc[nt] = zero;
    }
    // x-projection MFMAs (overlap the tail of the h DMA)
#pragma unroll
    for (int kcc = 0; kcc < 4; ++kcc)
#pragma unroll
      for (int nt = 0; nt < 4; ++nt)
        acc[nt] = __builtin_amdgcn_mfma_f32_16x16x32_bf16(xa[kcc], wih[kcc][nt], acc[nt], 0, 0, 0);

    // wait for all h-chunk DMAs to land in LDS (vmcnt(0); exp/lgkm unconstrained)
    __builtin_amdgcn_s_waitcnt(0x0F70);

    // h MFMAs: 8 chunks x 2 k-subchunks, swizzled A-frag reads
#pragma unroll
    for (int c = 0; c < 8; ++c) {
      const int base = wvoff + c * 1024 + m16 * 64;
#pragma unroll
      for (int k2 = 0; k2 < 2; ++k2) {
        const short8 a =
            *reinterpret_cast<const short8*>(&h_lds[base + ((k2 * 4 + quad) ^ m7) * 8]);
#pragma unroll
        for (int nt = 0; nt < 4; ++nt)
          acc[nt] = __builtin_amdgcn_mfma_f32_16x16x32_bf16(a, wf[c * 2 + k2][nt], acc[nt], 0, 0, 0);
      }
    }

    // partials -> LDS (C layout: row = quad*4+reg, col = nt*16 + lane&15)
#pragma unroll
    for (int nt = 0; nt < 4; ++nt)
#pragma unroll
      for (int i = 0; i < 4; ++i)
        red_lds[wv * 1024 + (quad * 4 + i) * 64 + nt * 16 + m16] = acc[nt][i];

    __syncthreads();  // barrier #1: partials visible to reduce threads

    // ---- reduce 4 k-partials + bias, tanh, store h_{t+1} tile, capture pad ----
    {
      float4 z = {0.f, 0.f, 0.f, 0.f};
#pragma unroll
      for (int ww = 0; ww < 4; ++ww) {
        const float4 p =
            *reinterpret_cast<const float4*>(&red_lds[ww * 1024 + rrow * 64 + rcb]);
        z.x += p.x; z.y += p.y; z.z += p.z; z.w += p.w;
      }
      const float t0 = tanhf(z.x + bias[0]);
      const float t1 = tanhf(z.y + bias[1]);
      const float t2 = tanhf(z.z + bias[2]);
      const float t3 = tanhf(z.w + bias[3]);
      unsigned long long pk = (unsigned long long)f2bf(t0) |
                              ((unsigned long long)f2bf(t1) << 16) |
                              ((unsigned long long)f2bf(t2) << 32) |
                              ((unsigned long long)f2bf(t3) << 48);
      // swizzled tile store: unit (rcb/8) ^ (row&7), half-unit (rcb>>2)&1
      const int toff = rrow * 64 + ((rcb >> 3) ^ (rrow & 7)) * 8 + ((rcb >> 2) & 1) * 4;
      unsigned short* hd = hbuf + (size_t)((t + 1) & 1) * (Bsz * Hsz) +
                           (size_t)(cg * 8 + rg) * 1024 + toff;
      // device-coherent store: write-through to L3 (the coherence point)
      __hip_atomic_store(reinterpret_cast<unsigned long long*>(hd), pk,
                         __ATOMIC_RELAXED, __HIP_MEMORY_SCOPE_AGENT);
      if (pad_lds[rrow] == t) {
        float4 o;
        o.x = t0; o.y = t1; o.z = t2; o.w = t3;
        *reinterpret_cast<float4*>(&hfinal[(size_t)(b0 + rrow) * Hsz + c0 + rcb]) = o;
      }
    }

    __syncthreads();  // barrier #2: full drain -> h tile at L3 before post

    if (have_next && tid == 0) {
      // single-writer flag: plain coherent store, no RMW
      __hip_atomic_store(flags + cg * 8 + rg, (unsigned)(t + 1),
                         __ATOMIC_RELAXED, __HIP_MEMORY_SCOPE_AGENT);
    }
  }
}

// out[b][o] = hfinal[b][:] . W_fc[o][:] + b_fc[o]; 8 b-tiles x 32 o-tiles
__global__ __launch_bounds__(64)
void fc_kernel(const float* __restrict__ hfinal, const float* __restrict__ W_fc,
               const float* __restrict__ b_fc, float* __restrict__ out) {
  const int lane = threadIdx.x & 63;
  const int m16 = lane & 15;
  const int quad = lane >> 4;
  const int b0 = (blockIdx.x & 7) * 16;
  const int o0 = (blockIdx.x >> 3) * 16;
  floatx4 acc = {0.f, 0.f, 0.f, 0.f};
  const float* ap = hfinal + (size_t)(b0 + m16) * Hsz + quad * 8;
  const float* bp = W_fc + (size_t)(o0 + m16) * Hsz + quad * 8;
#pragma unroll 4
  for (int kc = 0; kc < 64; ++kc) {
    short8 a, b;
#pragma unroll
    for (int j = 0; j < 8; ++j) a[j] = (short)f2bf(ap[kc * 32 + j]);
#pragma unroll
    for (int j = 0; j < 8; ++j) b[j] = (short)f2bf(bp[kc * 32 + j]);
    acc = __builtin_amdgcn_mfma_f32_16x16x32_bf16(a, b, acc, 0, 0, 0);
  }
  const float bias = b_fc[o0 + m16];
#pragma unroll
  for (int i = 0; i < 4; ++i)
    out[(size_t)(b0 + quad * 4 + i) * Osz + o0 + m16] = acc[i] + bias;
}

__global__ void zero_flags(unsigned int* f) { f[threadIdx.x] = 0u; }

extern "C" void kernel_launch(void* const* d_in, const int* in_sizes, int n_in,
                              void* d_out, int out_size, void* d_ws, size_t ws_size,
                              hipStream_t stream) {
  const float* x = (const float*)d_in[0];
  const float* h0 = (const float*)d_in[1];
  const float* W_ih = (const float*)d_in[2];
  const float* b_ih = (const float*)d_in[3];
  const float* W_hh = (const float*)d_in[4];
  const float* b_hh = (const float*)d_in[5];
  const float* W_fc = (const float*)d_in[6];
  const float* b_fc = (const float*)d_in[7];
  float* out = (float*)d_out;

  char* ws = (char*)d_ws;
  unsigned short* hbuf = (unsigned short*)ws;              // 1 MiB (2x 512KB tile slabs)
  float* hfinal = (float*)(ws + (1u << 20));               // 1 MiB
  unsigned int* flags = (unsigned int*)(ws + (2u << 20));  // 1 KiB (re-zeroed per launch)

  zero_flags<<<1, 256, 0, stream>>>(flags);
  rnn_kernel<<<256, 256, 0, stream>>>(x, h0, W_ih, b_ih, W_hh, b_hh, hbuf, hfinal, flags);
  fc_kernel<<<256, 64, 0, stream>>>(hfinal, W_fc, b_fc, out);
}

// Round 5
// 2277.149 us; speedup vs baseline: 1.2656x; 1.2656x over previous
//
#include <hip/hip_runtime.h>

// Problem: B=128, T=512, I=512, H=2048, O=512, steps = T-2 = 510.
// Persistent-RNN, R5: R4's per-producer flags + swizzled tiles, but the poll
// is ONE parallel ballot (all 64 lanes load the 8 flags, __all) instead of 8
// serialized round-trips (R4's bug: each poll's load-use forced vmcnt(0),
// draining the already-issued DMAs). DMAs now issue back-to-back after the
// single poll; h-MFMAs split vmcnt(8)/vmcnt(0) so chunks 0-3 compute while
// 4-7 stream in.
#define Bsz 128
#define Tsz 512
#define Isz 512
#define Hsz 2048
#define Osz 512
#define STEPS 510

typedef short short8 __attribute__((ext_vector_type(8)));
typedef float floatx4 __attribute__((ext_vector_type(4)));

// fp32 -> bf16 round-to-nearest-even (finite inputs only)
__device__ __forceinline__ unsigned short f2bf(float f) {
  unsigned int u = __builtin_bit_cast(unsigned int, f);
  u += 0x7FFFu + ((u >> 16) & 1u);
  return (unsigned short)(u >> 16);
}

// async global->LDS, 16B/lane; global src is per-lane (pass ptr + lane*16B),
// LDS dest is wave-uniform base (HW adds lane*16). AUX=0x11 (SC0|SC1):
// device-coherent read from L3, bypassing stale L1/L2.
template <int AUX>
__device__ __forceinline__ void gload_lds16(const void* g, void* l) {
  __builtin_amdgcn_global_load_lds(
      (const __attribute__((address_space(1))) void*)g,
      (__attribute__((address_space(3))) void*)l, 16, 0, AUX);
}

__global__ __launch_bounds__(256, 1)
void rnn_kernel(const float* __restrict__ x, const float* __restrict__ h0v,
                const float* __restrict__ W_ih, const float* __restrict__ b_ih,
                const float* __restrict__ W_hh, const float* __restrict__ b_hh,
                unsigned short* __restrict__ hbuf,  // [2][32 cg][8 rg][1024] swizzled bf16 tiles
                float* __restrict__ hfinal,         // [128][2048] f32
                unsigned int* __restrict__ flags)   // [32 cg][8 rg] step counters
{
  __shared__ short h_lds[4 * 8192];   // 64 KB: per-wave 8 chunk-tiles [16][64], swizzled
  __shared__ float red_lds[4 * 1024]; // 16 KB: k-split partials
  __shared__ int pad_lds[16];

  const int tid = threadIdx.x;
  const int lane = tid & 63;
  const int wv = tid >> 6;    // wave 0..3 -> k-quarter
  const int m16 = lane & 15;  // MFMA: A row / B col / C col
  const int quad = lane >> 4;
  const int m7 = m16 & 7;
  const int rg = blockIdx.x & 7;   // row group
  const int cg = blockIdx.x >> 3;  // col group 0..31
  const int b0 = rg * 16;
  const int c0 = cg * 64;
  const int kq = wv * 512;   // W_hh k-range for this wave
  const int kqx = wv * 128;  // W_ih k-range
  const int wvoff = wv * 8192;  // this wave's h_lds region (shorts)

  // ---- one-time: weight slices -> bf16 B-fragments in registers ----
  // B-frag: lane holds B[k = quad*8 + j][n = lane&15]
  short8 wf[16][4];  // [kchunk within quarter][ntile]
  short8 wih[4][4];
#pragma unroll
  for (int nt = 0; nt < 4; ++nt) {
    const int wrow = c0 + nt * 16 + m16;  // W row = output col j
    const float* base = W_hh + (size_t)wrow * Hsz + kq + quad * 8;
#pragma unroll
    for (int kc = 0; kc < 16; ++kc) {
      short8 v;
#pragma unroll
      for (int j = 0; j < 8; ++j) v[j] = (short)f2bf(base[kc * 32 + j]);
      wf[kc][nt] = v;
    }
    const float* basex = W_ih + (size_t)wrow * Isz + kqx + quad * 8;
#pragma unroll
    for (int kc = 0; kc < 4; ++kc) {
      short8 v;
#pragma unroll
      for (int j = 0; j < 8; ++j) v[j] = (short)f2bf(basex[kc * 32 + j]);
      wih[kc][nt] = v;
    }
  }

  // reduce-phase assignment: thread handles (row=tid>>4, 4 cols at 4*(tid&15))
  const int rrow = tid >> 4;
  const int rcb = (tid & 15) * 4;
  float bias[4];
#pragma unroll
  for (int i = 0; i < 4; ++i) bias[i] = b_ih[c0 + rcb + i] + b_hh[c0 + rcb + i];

  if (tid < 16)
    pad_lds[tid] = (int)x[(size_t)(b0 + tid) * (Tsz * Isz) + (size_t)(Tsz - 1) * Isz];

  // h_0 = h0 broadcast into this wave's 8 tiles (swizzled layout)
  for (int i = lane; i < 1024; i += 64) {  // i = 16B-unit index in wave region
    const int c = i >> 7;          // tile 0..7
    const int r = (i >> 3) & 15;   // row 0..15
    const int u = i & 7;           // unit 0..7
    const int k = kq + c * 64 + u * 8;
    short8 v;
#pragma unroll
    for (int j = 0; j < 8; ++j) v[j] = (short)f2bf(h0v[k + j]);
    *reinterpret_cast<short8*>(&h_lds[wvoff + c * 1024 + r * 64 + (u ^ (r & 7)) * 8]) = v;
  }

  // this wave's poll address: lane L watches producer cg = wv*8 + (L&7)
  const unsigned int* fp = flags + (size_t)(wv * 8 + (lane & 7)) * 8 + rg;

  for (int t = 0; t < STEPS; ++t) {
    const bool have_next = (t + 1) < STEPS;

    // x for this step: direct global->VGPR (drained once by the poll's wait)
    const float* xp = x + (size_t)(b0 + m16) * (Tsz * Isz) + (size_t)t * Isz + kqx + quad * 8;
    float4 xv[8];
#pragma unroll
    for (int kcc = 0; kcc < 4; ++kcc) {
      xv[2 * kcc] = *reinterpret_cast<const float4*>(xp + kcc * 32);
      xv[2 * kcc + 1] = *reinterpret_cast<const float4*>(xp + kcc * 32 + 4);
    }

    if (t > 0) {
      // ONE ballot poll: all 64 lanes load the wave's 8 producer flags
      while (!__all((int)(__hip_atomic_load(fp, __ATOMIC_RELAXED,
                                            __HIP_MEMORY_SCOPE_AGENT) >= (unsigned)t)))
        __builtin_amdgcn_s_sleep(1);
      // issue all 16 chunk DMAs back-to-back (no intervening waits)
      const unsigned short* hsrcp = hbuf + (size_t)(t & 1) * (Bsz * Hsz);
#pragma unroll
      for (int c = 0; c < 8; ++c) {
        const unsigned short* src = hsrcp + (size_t)((wv * 8 + c) * 8 + rg) * 1024;
        gload_lds16<0x11>(src + lane * 8, &h_lds[wvoff + c * 1024]);
        gload_lds16<0x11>(src + 512 + lane * 8, &h_lds[wvoff + c * 1024 + 512]);
      }
    }

    // convert x to A-frags (xv already complete: drained by poll's first wait)
    short8 xa[4];
#pragma unroll
    for (int kcc = 0; kcc < 4; ++kcc) {
      short8 a;
      a[0] = (short)f2bf(xv[2 * kcc].x);
      a[1] = (short)f2bf(xv[2 * kcc].y);
      a[2] = (short)f2bf(xv[2 * kcc].z);
      a[3] = (short)f2bf(xv[2 * kcc].w);
      a[4] = (short)f2bf(xv[2 * kcc + 1].x);
      a[5] = (short)f2bf(xv[2 * kcc + 1].y);
      a[6] = (short)f2bf(xv[2 * kcc + 1].z);
      a[7] = (short)f2bf(xv[2 * kcc + 1].w);
      xa[kcc] = a;
    }

    floatx4 acc[4];
#pragma unroll
    for (int nt = 0; nt < 4; ++nt) {
      floatx4 zero = {0.f, 0.f, 0.f, 0.f};
      acc[nt] = zero;
    }
    // x-projection MFMAs (overlap DMA stream)
#pragma unroll
    for (int kcc = 0; kcc < 4; ++kcc)
#pragma unroll
      for (int nt = 0; nt < 4; ++nt)
        acc[nt] = __builtin_amdgcn_mfma_f32_16x16x32_bf16(xa[kcc], wih[kcc][nt], acc[nt], 0, 0, 0);

    // chunks 0-3 landed (vmcnt retires oldest-first: 16 outstanding -> 8)
    __builtin_amdgcn_s_waitcnt(0x0F78);  // vmcnt(8)
#pragma unroll
    for (int c = 0; c < 4; ++c) {
      const int base = wvoff + c * 1024 + m16 * 64;
#pragma unroll
      for (int k2 = 0; k2 < 2; ++k2) {
        const short8 a =
            *reinterpret_cast<const short8*>(&h_lds[base + ((k2 * 4 + quad) ^ m7) * 8]);
#pragma unroll
        for (int nt = 0; nt < 4; ++nt)
          acc[nt] = __builtin_amdgcn_mfma_f32_16x16x32_bf16(a, wf[c * 2 + k2][nt], acc[nt], 0, 0, 0);
      }
    }
    // chunks 4-7 landed
    __builtin_amdgcn_s_waitcnt(0x0F70);  // vmcnt(0)
#pragma unroll
    for (int c = 4; c < 8; ++c) {
      const int base = wvoff + c * 1024 + m16 * 64;
#pragma unroll
      for (int k2 = 0; k2 < 2; ++k2) {
        const short8 a =
            *reinterpret_cast<const short8*>(&h_lds[base + ((k2 * 4 + quad) ^ m7) * 8]);
#pragma unroll
        for (int nt = 0; nt < 4; ++nt)
          acc[nt] = __builtin_amdgcn_mfma_f32_16x16x32_bf16(a, wf[c * 2 + k2][nt], acc[nt], 0, 0, 0);
      }
    }

    // partials -> LDS (C layout: row = quad*4+reg, col = nt*16 + lane&15)
#pragma unroll
    for (int nt = 0; nt < 4; ++nt)
#pragma unroll
      for (int i = 0; i < 4; ++i)
        red_lds[wv * 1024 + (quad * 4 + i) * 64 + nt * 16 + m16] = acc[nt][i];

    __syncthreads();  // barrier #1: partials visible to reduce threads

    // ---- reduce 4 k-partials + bias, tanh, store h_{t+1} tile, capture pad ----
    {
      float4 z = {0.f, 0.f, 0.f, 0.f};
#pragma unroll
      for (int ww = 0; ww < 4; ++ww) {
        const float4 p =
            *reinterpret_cast<const float4*>(&red_lds[ww * 1024 + rrow * 64 + rcb]);
        z.x += p.x; z.y += p.y; z.z += p.z; z.w += p.w;
      }
      const float t0 = tanhf(z.x + bias[0]);
      const float t1 = tanhf(z.y + bias[1]);
      const float t2 = tanhf(z.z + bias[2]);
      const float t3 = tanhf(z.w + bias[3]);
      unsigned long long pk = (unsigned long long)f2bf(t0) |
                              ((unsigned long long)f2bf(t1) << 16) |
                              ((unsigned long long)f2bf(t2) << 32) |
                              ((unsigned long long)f2bf(t3) << 48);
      // swizzled tile store: unit (rcb/8) ^ (row&7), half-unit (rcb>>2)&1
      const int toff = rrow * 64 + ((rcb >> 3) ^ (rrow & 7)) * 8 + ((rcb >> 2) & 1) * 4;
      unsigned short* hd = hbuf + (size_t)((t + 1) & 1) * (Bsz * Hsz) +
                           (size_t)(cg * 8 + rg) * 1024 + toff;
      // device-coherent store: write-through to L3 (the coherence point)
      __hip_atomic_store(reinterpret_cast<unsigned long long*>(hd), pk,
                         __ATOMIC_RELAXED, __HIP_MEMORY_SCOPE_AGENT);
      if (pad_lds[rrow] == t) {
        float4 o;
        o.x = t0; o.y = t1; o.z = t2; o.w = t3;
        *reinterpret_cast<float4*>(&hfinal[(size_t)(b0 + rrow) * Hsz + c0 + rcb]) = o;
      }
    }

    __syncthreads();  // barrier #2: full drain -> h tile at L3 before post

    if (have_next && tid == 0) {
      // single-writer flag: plain coherent store, no RMW
      __hip_atomic_store(flags + cg * 8 + rg, (unsigned)(t + 1),
                         __ATOMIC_RELAXED, __HIP_MEMORY_SCOPE_AGENT);
    }
  }
}

// out[b][o] = hfinal[b][:] . W_fc[o][:] + b_fc[o]; 8 b-tiles x 32 o-tiles
__global__ __launch_bounds__(64)
void fc_kernel(const float* __restrict__ hfinal, const float* __restrict__ W_fc,
               const float* __restrict__ b_fc, float* __restrict__ out) {
  const int lane = threadIdx.x & 63;
  const int m16 = lane & 15;
  const int quad = lane >> 4;
  const int b0 = (blockIdx.x & 7) * 16;
  const int o0 = (blockIdx.x >> 3) * 16;
  floatx4 acc = {0.f, 0.f, 0.f, 0.f};
  const float* ap = hfinal + (size_t)(b0 + m16) * Hsz + quad * 8;
  const float* bp = W_fc + (size_t)(o0 + m16) * Hsz + quad * 8;
#pragma unroll 4
  for (int kc = 0; kc < 64; ++kc) {
    short8 a, b;
#pragma unroll
    for (int j = 0; j < 8; ++j) a[j] = (short)f2bf(ap[kc * 32 + j]);
#pragma unroll
    for (int j = 0; j < 8; ++j) b[j] = (short)f2bf(bp[kc * 32 + j]);
    acc = __builtin_amdgcn_mfma_f32_16x16x32_bf16(a, b, acc, 0, 0, 0);
  }
  const float bias = b_fc[o0 + m16];
#pragma unroll
  for (int i = 0; i < 4; ++i)
    out[(size_t)(b0 + quad * 4 + i) * Osz + o0 + m16] = acc[i] + bias;
}

__global__ void zero_flags(unsigned int* f) { f[threadIdx.x] = 0u; }

extern "C" void kernel_launch(void* const* d_in, const int* in_sizes, int n_in,
                              void* d_out, int out_size, void* d_ws, size_t ws_size,
                              hipStream_t stream) {
  const float* x = (const float*)d_in[0];
  const float* h0 = (const float*)d_in[1];
  const float* W_ih = (const float*)d_in[2];
  const float* b_ih = (const float*)d_in[3];
  const float* W_hh = (const float*)d_in[4];
  const float* b_hh = (const float*)d_in[5];
  const float* W_fc = (const float*)d_in[6];
  const float* b_fc = (const float*)d_in[7];
  float* out = (float*)d_out;

  char* ws = (char*)d_ws;
  unsigned short* hbuf = (unsigned short*)ws;              // 1 MiB (2x 512KB tile slabs)
  float* hfinal = (float*)(ws + (1u << 20));               // 1 MiB
  unsigned int* flags = (unsigned int*)(ws + (2u << 20));  // 1 KiB (re-zeroed per launch)

  zero_flags<<<1, 256, 0, stream>>>(flags);
  rnn_kernel<<<256, 256, 0, stream>>>(x, h0, W_ih, b_ih, W_hh, b_hh, hbuf, hfinal, flags);
  fc_kernel<<<256, 64, 0, stream>>>(hfinal, W_fc, b_fc, out);
}

// Round 6
// 2069.926 us; speedup vs baseline: 1.3923x; 1.1001x over previous
//
#include <hip/hip_runtime.h>

// Problem: B=128, T=512, I=512, H=2048, O=512, steps = T-2 = 510.
// Persistent-RNN, R6: keep R5's per-producer flags + ballot poll + swizzled
// tiles, but move the h exchange into the per-XCD L2 when legal:
//   - Runtime colocation check: each block publishes s_getreg(HW_REG_XCC_ID);
//     each row-group verifies all 32 members share one XCD. If yes (expected
//     under round-robin dispatch, rg = bid&7 == bid%8), h stores become plain
//     write-back (dirty in the SHARED physical L2 -> unconditionally coherent
//     for same-L2 readers) and h DMA uses aux=0x01 (SC0: bypass L1, read L2).
//     If no, byte-for-byte fallback to R5's device-coherent L3 path.
//   - Flags stay device-scope (negligible traffic).
//   - tanhf -> exact identity 1 - 2*rcp(e^{2x}+1) (~4 VALU ops vs ~30).
#define Bsz 128
#define Tsz 512
#define Isz 512
#define Hsz 2048
#define Osz 512
#define STEPS 510

typedef short short8 __attribute__((ext_vector_type(8)));
typedef float floatx4 __attribute__((ext_vector_type(4)));

// fp32 -> bf16 round-to-nearest-even (finite inputs only)
__device__ __forceinline__ unsigned short f2bf(float f) {
  unsigned int u = __builtin_bit_cast(unsigned int, f);
  u += 0x7FFFu + ((u >> 16) & 1u);
  return (unsigned short)(u >> 16);
}

// exact identity tanh(x) = 1 - 2/(e^{2x}+1); exp+rcp ~1ulp, abs err ~1e-7
__device__ __forceinline__ float tanh_fast(float x) {
  const float e = __expf(2.f * x);
  return 1.f - 2.f * __builtin_amdgcn_rcpf(e + 1.f);
}

// async global->LDS, 16B/lane; global src per-lane (ptr + lane*16B), LDS dest
// wave-uniform base. AUX CPol: 0x11 = SC0|SC1 (device-coherent, read L3),
// 0x01 = SC0 (bypass L1 only; read shared XCD L2 -- hits producer-dirty lines)
template <int AUX>
__device__ __forceinline__ void gload_lds16(const void* g, void* l) {
  __builtin_amdgcn_global_load_lds(
      (const __attribute__((address_space(1))) void*)g,
      (__attribute__((address_space(3))) void*)l, 16, 0, AUX);
}

__global__ __launch_bounds__(256, 1)
void rnn_kernel(const float* __restrict__ x, const float* __restrict__ h0v,
                const float* __restrict__ W_ih, const float* __restrict__ b_ih,
                const float* __restrict__ W_hh, const float* __restrict__ b_hh,
                unsigned short* __restrict__ hbuf,  // [2][32 cg][8 rg][1024] swizzled bf16 tiles
                float* __restrict__ hfinal,         // [128][2048] f32
                unsigned int* __restrict__ flags,   // [32 cg][8 rg] step counters
                unsigned int* __restrict__ xcc_arr) // [8 rg][32 cg] XCC id + 1
{
  __shared__ short h_lds[4 * 8192];   // 64 KB: per-wave 8 chunk-tiles [16][64], swizzled
  __shared__ float red_lds[4 * 1024]; // 16 KB: k-split partials
  __shared__ int pad_lds[16];
  __shared__ unsigned int mode_lds;   // 1 = same-XCD L2 exchange legal

  const int tid = threadIdx.x;
  const int lane = tid & 63;
  const int wv = tid >> 6;    // wave 0..3 -> k-quarter
  const int m16 = lane & 15;  // MFMA: A row / B col / C col
  const int quad = lane >> 4;
  const int m7 = m16 & 7;
  const int rg = blockIdx.x & 7;   // row group (bid%8 -> XCD under round-robin)
  const int cg = blockIdx.x >> 3;  // col group 0..31
  const int b0 = rg * 16;
  const int c0 = cg * 64;
  const int kq = wv * 512;   // W_hh k-range for this wave
  const int kqx = wv * 128;  // W_ih k-range
  const int wvoff = wv * 8192;  // this wave's h_lds region (shorts)

  // ---- runtime XCD-colocation check (publish + verify all 32 rg members) ----
  {
    unsigned int xcc;
    asm volatile("s_getreg_b32 %0, hwreg(HW_REG_XCC_ID)" : "=s"(xcc));
    if (tid == 0)
      __hip_atomic_store(&xcc_arr[rg * 32 + cg], xcc + 1u, __ATOMIC_RELAXED,
                         __HIP_MEMORY_SCOPE_AGENT);
    if (wv == 0) {
      const unsigned int* ap = &xcc_arr[rg * 32 + (lane & 31)];
      unsigned int v;
      do {
        v = __hip_atomic_load(ap, __ATOMIC_RELAXED, __HIP_MEMORY_SCOPE_AGENT);
        if (__all((int)(v != 0u))) break;
        __builtin_amdgcn_s_sleep(2);
      } while (true);
      const int same = __all((int)(v == xcc + 1u));
      if (tid == 0) mode_lds = (unsigned int)same;
    }
  }

  // ---- one-time: weight slices -> bf16 B-fragments in registers ----
  // B-frag: lane holds B[k = quad*8 + j][n = lane&15]
  short8 wf[16][4];  // [kchunk within quarter][ntile]
  short8 wih[4][4];
#pragma unroll
  for (int nt = 0; nt < 4; ++nt) {
    const int wrow = c0 + nt * 16 + m16;  // W row = output col j
    const float* base = W_hh + (size_t)wrow * Hsz + kq + quad * 8;
#pragma unroll
    for (int kc = 0; kc < 16; ++kc) {
      short8 v;
#pragma unroll
      for (int j = 0; j < 8; ++j) v[j] = (short)f2bf(base[kc * 32 + j]);
      wf[kc][nt] = v;
    }
    const float* basex = W_ih + (size_t)wrow * Isz + kqx + quad * 8;
#pragma unroll
    for (int kc = 0; kc < 4; ++kc) {
      short8 v;
#pragma unroll
      for (int j = 0; j < 8; ++j) v[j] = (short)f2bf(basex[kc * 32 + j]);
      wih[kc][nt] = v;
    }
  }

  // reduce-phase assignment: thread handles (row=tid>>4, 4 cols at 4*(tid&15))
  const int rrow = tid >> 4;
  const int rcb = (tid & 15) * 4;
  float bias[4];
#pragma unroll
  for (int i = 0; i < 4; ++i) bias[i] = b_ih[c0 + rcb + i] + b_hh[c0 + rcb + i];

  if (tid < 16)
    pad_lds[tid] = (int)x[(size_t)(b0 + tid) * (Tsz * Isz) + (size_t)(Tsz - 1) * Isz];

  // h_0 = h0 broadcast into this wave's 8 tiles (swizzled layout)
  for (int i = lane; i < 1024; i += 64) {  // i = 16B-unit index in wave region
    const int c = i >> 7;          // tile 0..7
    const int r = (i >> 3) & 15;   // row 0..15
    const int u = i & 7;           // unit 0..7
    const int k = kq + c * 64 + u * 8;
    short8 v;
#pragma unroll
    for (int j = 0; j < 8; ++j) v[j] = (short)f2bf(h0v[k + j]);
    *reinterpret_cast<short8*>(&h_lds[wvoff + c * 1024 + r * 64 + (u ^ (r & 7)) * 8]) = v;
  }

  __syncthreads();  // mode_lds + pad_lds visible to all waves
  const bool use_l2 = (mode_lds != 0u);

  // this wave's poll address: lane L watches producer cg = wv*8 + (L&7)
  const unsigned int* fp = flags + (size_t)(wv * 8 + (lane & 7)) * 8 + rg;

  for (int t = 0; t < STEPS; ++t) {
    const bool have_next = (t + 1) < STEPS;

    // x for this step: direct global->VGPR (drained once by the poll's wait)
    const float* xp = x + (size_t)(b0 + m16) * (Tsz * Isz) + (size_t)t * Isz + kqx + quad * 8;
    float4 xv[8];
#pragma unroll
    for (int kcc = 0; kcc < 4; ++kcc) {
      xv[2 * kcc] = *reinterpret_cast<const float4*>(xp + kcc * 32);
      xv[2 * kcc + 1] = *reinterpret_cast<const float4*>(xp + kcc * 32 + 4);
    }

    if (t > 0) {
      // ONE ballot poll: all 64 lanes load the wave's 8 producer flags
      while (!__all((int)(__hip_atomic_load(fp, __ATOMIC_RELAXED,
                                            __HIP_MEMORY_SCOPE_AGENT) >= (unsigned)t)))
        __builtin_amdgcn_s_sleep(1);
      // issue all 16 chunk DMAs back-to-back (no intervening waits)
      const unsigned short* hsrcp = hbuf + (size_t)(t & 1) * (Bsz * Hsz);
      if (use_l2) {
#pragma unroll
        for (int c = 0; c < 8; ++c) {
          const unsigned short* src = hsrcp + (size_t)((wv * 8 + c) * 8 + rg) * 1024;
          gload_lds16<0x01>(src + lane * 8, &h_lds[wvoff + c * 1024]);
          gload_lds16<0x01>(src + 512 + lane * 8, &h_lds[wvoff + c * 1024 + 512]);
        }
      } else {
#pragma unroll
        for (int c = 0; c < 8; ++c) {
          const unsigned short* src = hsrcp + (size_t)((wv * 8 + c) * 8 + rg) * 1024;
          gload_lds16<0x11>(src + lane * 8, &h_lds[wvoff + c * 1024]);
          gload_lds16<0x11>(src + 512 + lane * 8, &h_lds[wvoff + c * 1024 + 512]);
        }
      }
    }

    // convert x to A-frags (xv already complete: drained by poll's first wait)
    short8 xa[4];
#pragma unroll
    for (int kcc = 0; kcc < 4; ++kcc) {
      short8 a;
      a[0] = (short)f2bf(xv[2 * kcc].x);
      a[1] = (short)f2bf(xv[2 * kcc].y);
      a[2] = (short)f2bf(xv[2 * kcc].z);
      a[3] = (short)f2bf(xv[2 * kcc].w);
      a[4] = (short)f2bf(xv[2 * kcc + 1].x);
      a[5] = (short)f2bf(xv[2 * kcc + 1].y);
      a[6] = (short)f2bf(xv[2 * kcc + 1].z);
      a[7] = (short)f2bf(xv[2 * kcc + 1].w);
      xa[kcc] = a;
    }

    floatx4 acc[4];
#pragma unroll
    for (int nt = 0; nt < 4; ++nt) {
      floatx4 zero = {0.f, 0.f, 0.f, 0.f};
      acc[nt] = zero;
    }
    // x-projection MFMAs (overlap DMA stream)
#pragma unroll
    for (int kcc = 0; kcc < 4; ++kcc)
#pragma unroll
      for (int nt = 0; nt < 4; ++nt)
        acc[nt] = __builtin_amdgcn_mfma_f32_16x16x32_bf16(xa[kcc], wih[kcc][nt], acc[nt], 0, 0, 0);

    // chunks 0-3 landed (vmcnt retires oldest-first: 16 outstanding -> 8)
    __builtin_amdgcn_s_waitcnt(0x0F78);  // vmcnt(8)
#pragma unroll
    for (int c = 0; c < 4; ++c) {
      const int base = wvoff + c * 1024 + m16 * 64;
#pragma unroll
      for (int k2 = 0; k2 < 2; ++k2) {
        const short8 a =
            *reinterpret_cast<const short8*>(&h_lds[base + ((k2 * 4 + quad) ^ m7) * 8]);
#pragma unroll
        for (int nt = 0; nt < 4; ++nt)
          acc[nt] = __builtin_amdgcn_mfma_f32_16x16x32_bf16(a, wf[c * 2 + k2][nt], acc[nt], 0, 0, 0);
      }
    }
    // chunks 4-7 landed
    __builtin_amdgcn_s_waitcnt(0x0F70);  // vmcnt(0)
#pragma unroll
    for (int c = 4; c < 8; ++c) {
      const int base = wvoff + c * 1024 + m16 * 64;
#pragma unroll
      for (int k2 = 0; k2 < 2; ++k2) {
        const short8 a =
            *reinterpret_cast<const short8*>(&h_lds[base + ((k2 * 4 + quad) ^ m7) * 8]);
#pragma unroll
        for (int nt = 0; nt < 4; ++nt)
          acc[nt] = __builtin_amdgcn_mfma_f32_16x16x32_bf16(a, wf[c * 2 + k2][nt], acc[nt], 0, 0, 0);
      }
    }

    // partials -> LDS (C layout: row = quad*4+reg, col = nt*16 + lane&15)
#pragma unroll
    for (int nt = 0; nt < 4; ++nt)
#pragma unroll
      for (int i = 0; i < 4; ++i)
        red_lds[wv * 1024 + (quad * 4 + i) * 64 + nt * 16 + m16] = acc[nt][i];

    __syncthreads();  // barrier #1: partials visible to reduce threads

    // ---- reduce 4 k-partials + bias, tanh, store h_{t+1} tile, capture pad ----
    {
      float4 z = {0.f, 0.f, 0.f, 0.f};
#pragma unroll
      for (int ww = 0; ww < 4; ++ww) {
        const float4 p =
            *reinterpret_cast<const float4*>(&red_lds[ww * 1024 + rrow * 64 + rcb]);
        z.x += p.x; z.y += p.y; z.z += p.z; z.w += p.w;
      }
      const float t0 = tanh_fast(z.x + bias[0]);
      const float t1 = tanh_fast(z.y + bias[1]);
      const float t2 = tanh_fast(z.z + bias[2]);
      const float t3 = tanh_fast(z.w + bias[3]);
      unsigned long long pk = (unsigned long long)f2bf(t0) |
                              ((unsigned long long)f2bf(t1) << 16) |
                              ((unsigned long long)f2bf(t2) << 32) |
                              ((unsigned long long)f2bf(t3) << 48);
      // swizzled tile store: unit (rcb/8) ^ (row&7), half-unit (rcb>>2)&1
      const int toff = rrow * 64 + ((rcb >> 3) ^ (rrow & 7)) * 8 + ((rcb >> 2) & 1) * 4;
      unsigned short* hd = hbuf + (size_t)((t + 1) & 1) * (Bsz * Hsz) +
                           (size_t)(cg * 8 + rg) * 1024 + toff;
      if (use_l2) {
        // plain write-back store: dirty in the SHARED XCD L2 (coherent for
        // same-L2 readers; eviction goes to L3 which SC0 readers then fill from)
        *reinterpret_cast<unsigned long long*>(hd) = pk;
      } else {
        // device-coherent store: write-through to L3 (the coherence point)
        __hip_atomic_store(reinterpret_cast<unsigned long long*>(hd), pk,
                           __ATOMIC_RELAXED, __HIP_MEMORY_SCOPE_AGENT);
      }
      if (pad_lds[rrow] == t) {
        float4 o;
        o.x = t0; o.y = t1; o.z = t2; o.w = t3;
        *reinterpret_cast<float4*>(&hfinal[(size_t)(b0 + rrow) * Hsz + c0 + rcb]) = o;
      }
    }

    __syncthreads();  // barrier #2: full vmcnt drain -> h committed before post

    if (have_next && tid == 0) {
      // single-writer flag: plain coherent store, no RMW
      __hip_atomic_store(flags + cg * 8 + rg, (unsigned)(t + 1),
                         __ATOMIC_RELAXED, __HIP_MEMORY_SCOPE_AGENT);
    }
  }
}

// out[b][o] = hfinal[b][:] . W_fc[o][:] + b_fc[o]; 8 b-tiles x 32 o-tiles
__global__ __launch_bounds__(64)
void fc_kernel(const float* __restrict__ hfinal, const float* __restrict__ W_fc,
               const float* __restrict__ b_fc, float* __restrict__ out) {
  const int lane = threadIdx.x & 63;
  const int m16 = lane & 15;
  const int quad = lane >> 4;
  const int b0 = (blockIdx.x & 7) * 16;
  const int o0 = (blockIdx.x >> 3) * 16;
  floatx4 acc = {0.f, 0.f, 0.f, 0.f};
  const float* ap = hfinal + (size_t)(b0 + m16) * Hsz + quad * 8;
  const float* bp = W_fc + (size_t)(o0 + m16) * Hsz + quad * 8;
#pragma unroll 4
  for (int kc = 0; kc < 64; ++kc) {
    short8 a, b;
#pragma unroll
    for (int j = 0; j < 8; ++j) a[j] = (short)f2bf(ap[kc * 32 + j]);
#pragma unroll
    for (int j = 0; j < 8; ++j) b[j] = (short)f2bf(bp[kc * 32 + j]);
    acc = __builtin_amdgcn_mfma_f32_16x16x32_bf16(a, b, acc, 0, 0, 0);
  }
  const float bias = b_fc[o0 + m16];
#pragma unroll
  for (int i = 0; i < 4; ++i)
    out[(size_t)(b0 + quad * 4 + i) * Osz + o0 + m16] = acc[i] + bias;
}

__global__ void zero_flags(unsigned int* f) { f[blockIdx.x * 256 + threadIdx.x] = 0u; }

extern "C" void kernel_launch(void* const* d_in, const int* in_sizes, int n_in,
                              void* d_out, int out_size, void* d_ws, size_t ws_size,
                              hipStream_t stream) {
  const float* x = (const float*)d_in[0];
  const float* h0 = (const float*)d_in[1];
  const float* W_ih = (const float*)d_in[2];
  const float* b_ih = (const float*)d_in[3];
  const float* W_hh = (const float*)d_in[4];
  const float* b_hh = (const float*)d_in[5];
  const float* W_fc = (const float*)d_in[6];
  const float* b_fc = (const float*)d_in[7];
  float* out = (float*)d_out;

  char* ws = (char*)d_ws;
  unsigned short* hbuf = (unsigned short*)ws;              // 1 MiB (2x 512KB tile slabs)
  float* hfinal = (float*)(ws + (1u << 20));               // 1 MiB
  unsigned int* flags = (unsigned int*)(ws + (2u << 20));  // 1 KiB flags
  unsigned int* xcc_arr = flags + 256;                     // 1 KiB xcc ids

  zero_flags<<<2, 256, 0, stream>>>(flags);  // zero flags + xcc_arr
  rnn_kernel<<<256, 256, 0, stream>>>(x, h0, W_ih, b_ih, W_hh, b_hh, hbuf, hfinal,
                                      flags, xcc_arr);
  fc_kernel<<<256, 64, 0, stream>>>(hfinal, W_fc, b_fc, out);
}